// Round 3
// baseline (28444.815 us; speedup 1.0000x reference)
//
#include <hip/hip_runtime.h>
#include <hip/hip_cooperative_groups.h>

namespace cg = cooperative_groups;

// Eikonal 3D — 288 Godunov Jacobi sweeps, 96^3 grid.
// Round 3: single persistent cooperative kernel, grid.sync() between sweeps.
// 864 blocks x 256 threads, 1 float4-quad of k-cells per thread (exact cover).
// Ping-pong: A = d_out, B = d_ws; it=287 (odd) writes A -> final in d_out.

#define N    96
#define N2   (96 * 96)
#define N3   (96 * 96 * 96)
#define NQ   (N3 / 4)
#define QROW (N / 4)
#define BIGV 1e5f
#define SRC_IDX (48 * N2 + 48 * N + 48)
#define NITER 288

__device__ __forceinline__ float godunov_cell(float a, float b, float c,
                                              float fh, float uc) {
    float lo  = fminf(fminf(a, b), c);
    float hi  = fmaxf(fmaxf(a, b), c);
    float mid = a + b + c - lo - hi;          // match JAX expression order

    float u1 = lo + fh;

    float dlm = lo - mid;
    float d2  = 2.0f * fh * fh - dlm * dlm;
    float u2  = (d2 > 0.0f) ? 0.5f * (lo + mid + sqrtf(d2)) : BIGV;

    float s  = lo + mid + hi;
    float q  = lo * lo + mid * mid + hi * hi - fh * fh;
    float d3 = s * s - 3.0f * q;
    float u3 = (d3 > 0.0f) ? (s + sqrtf(d3)) / 3.0f : BIGV;

    float cand = (u1 <= mid) ? u1 : ((u2 <= hi) ? u2 : u3);
    return fminf(uc, cand);
}

__global__ __launch_bounds__(256) void eik_coop(const float* __restrict__ f,
                                                float* __restrict__ A,
                                                float* __restrict__ B) {
    cg::grid_group grid = cg::this_grid();

    const int q  = blockIdx.x * 256 + threadIdx.x;   // [0, NQ)
    const int k0 = (q % QROW) * 4;
    const int t  = q / QROW;
    const int j  = t % N;
    const int i  = t / N;
    const int base = i * N2 + j * N + k0;            // 16B-aligned

    const bool has_src = (base == SRC_IDX);          // src k=48 -> lane .x
    const float4 BIG4 = make_float4(BIGV, BIGV, BIGV, BIGV);

    // ---- init u0 into A ----
    float4 u0 = BIG4;
    if (has_src) u0.x = 0.0f;
    *reinterpret_cast<float4*>(A + base) = u0;

    const float4 f4 = *reinterpret_cast<const float4*>(f + base);

    grid.sync();

    // ---- 288 sweeps ----
    for (int it = 0; it < NITER; ++it) {
        const float* __restrict__ u  = (it & 1) ? B : A;
        float*       __restrict__ un = (it & 1) ? A : B;

        float4 uc = *reinterpret_cast<const float4*>(u + base);
        float4 xm = (i > 0)     ? *reinterpret_cast<const float4*>(u + base - N2) : BIG4;
        float4 xp = (i < N - 1) ? *reinterpret_cast<const float4*>(u + base + N2) : BIG4;
        float4 ym = (j > 0)     ? *reinterpret_cast<const float4*>(u + base - N)  : BIG4;
        float4 yp = (j < N - 1) ? *reinterpret_cast<const float4*>(u + base + N)  : BIG4;
        float  zl = (k0 > 0)     ? u[base - 1] : BIGV;
        float  zr = (k0 < N - 4) ? u[base + 4] : BIGV;

        float4 un4;
        float ax, bx, cx;
        // cell 0
        ax = fminf(xm.x, xp.x);
        bx = fminf(ym.x, yp.x);
        cx = fminf(zl,   uc.y);
        un4.x = godunov_cell(ax, bx, cx, f4.x, uc.x);
        // cell 1
        ax = fminf(xm.y, xp.y);
        bx = fminf(ym.y, yp.y);
        cx = fminf(uc.x, uc.z);
        un4.y = godunov_cell(ax, bx, cx, f4.y, uc.y);
        // cell 2
        ax = fminf(xm.z, xp.z);
        bx = fminf(ym.z, yp.z);
        cx = fminf(uc.y, uc.w);
        un4.z = godunov_cell(ax, bx, cx, f4.z, uc.z);
        // cell 3
        ax = fminf(xm.w, xp.w);
        bx = fminf(ym.w, yp.w);
        cx = fminf(uc.z, zr);
        un4.w = godunov_cell(ax, bx, cx, f4.w, uc.w);

        if (has_src) un4.x = 0.0f;                   // pin source each sweep
        *reinterpret_cast<float4*>(un + base) = un4;

        grid.sync();
    }
}

extern "C" void kernel_launch(void* const* d_in, const int* in_sizes, int n_in,
                              void* d_out, int out_size, void* d_ws, size_t ws_size,
                              hipStream_t stream) {
    const float* f = (const float*)d_in[0];
    float* A = (float*)d_out;
    float* B = (float*)d_ws;

    void* args[] = { (void*)&f, (void*)&A, (void*)&B };
    hipLaunchCooperativeKernel((void*)eik_coop, dim3(NQ / 256), dim3(256),
                               args, 0, stream);
}

// Round 4
// 3101.840 us; speedup vs baseline: 9.1703x; 9.1703x over previous
//
#include <hip/hip_runtime.h>

// Eikonal 3D — 288 Godunov Jacobi sweeps, 96^3 grid.
// Round 4: LDS temporal blocking — 4 sweeps per dispatch, 72 dispatches.
// Block = 12^3 output tile; stages 20^3 input (halo 4) into LDS, runs 4
// in-LDS Jacobi sub-steps over shrinking regions 18^3,16^3,14^3,12^3.
// Bit-exact vs plain Jacobi: outside-domain cells held at BIG, source pinned
// by global index (also inside halos), identical per-cell arithmetic.
// Ping-pong: A = d_out, B = d_ws; 72 (even) fused dispatches -> final in A.

#define N    96
#define N2   (96 * 96)
#define N3   (96 * 96 * 96)
#define BIGV 1e5f
#define SRC_IDX ((48 * N + 48) * N + 48)

#define TS   12            // output tile edge
#define S    4             // sweeps per dispatch
#define IN   (TS + 2 * S)  // 20: staged input tile edge
#define IN2  (IN * IN)
#define IN3  (IN * IN * IN)
#define NT   (N / TS)      // 8 tiles per axis
#define NSTEPS_TOTAL 288
#define NDISP (NSTEPS_TOTAL / S)   // 72

__global__ __launch_bounds__(256) void eik_init(float* __restrict__ u) {
    int idx = blockIdx.x * 256 + threadIdx.x;
    u[idx] = (idx == SRC_IDX) ? 0.0f : BIGV;
}

template <int R, int O>
__device__ __forceinline__ void substep(const float* __restrict__ src,
                                        float* __restrict__ dst,
                                        const float* __restrict__ f,
                                        int gx0, int gy0, int gz0) {
    constexpr int R2 = R * R;
    constexpr int R3 = R * R * R;
    for (int idx = threadIdx.x; idx < R3; idx += 256) {
        int lz  = idx / R2 + O;
        int rem = idx % R2;
        int ly  = rem / R + O;
        int lx  = rem % R + O;
        int li  = (lz * IN + ly) * IN + lx;

        int gx = gx0 + lx, gy = gy0 + ly, gz = gz0 + lz;
        bool inside = ((unsigned)gx < N) && ((unsigned)gy < N) && ((unsigned)gz < N);
        if (!inside) { dst[li] = BIGV; continue; }

        float uc = src[li];
        float a  = fminf(src[li - IN2], src[li + IN2]);   // z-axis (slowest)
        float b  = fminf(src[li - IN],  src[li + IN]);    // y-axis
        float c  = fminf(src[li - 1],   src[li + 1]);     // x-axis (fastest)
        float lo = fminf(fminf(a, b), c);

        int gidx = (gz * N + gy) * N + gx;
        float v;
        if (lo >= BIGV) {
            v = uc;                       // exact: cand >= BIG, un = min(uc, cand) = uc
        } else {
            float hi  = fmaxf(fmaxf(a, b), c);
            float mid = a + b + c - lo - hi;
            float fh  = f[gidx];

            float u1  = lo + fh;
            float dlm = lo - mid;
            float d2  = 2.0f * fh * fh - dlm * dlm;
            float u2  = (d2 > 0.0f) ? 0.5f * (lo + mid + sqrtf(d2)) : BIGV;

            float s  = lo + mid + hi;
            float qq = lo * lo + mid * mid + hi * hi - fh * fh;
            float d3 = s * s - 3.0f * qq;
            float u3 = (d3 > 0.0f) ? (s + sqrtf(d3)) / 3.0f : BIGV;

            float cand = (u1 <= mid) ? u1 : ((u2 <= hi) ? u2 : u3);
            v = fminf(uc, cand);
        }
        if (gidx == SRC_IDX) v = 0.0f;    // pin source (also in halo copies)
        dst[li] = v;
    }
}

__global__ __launch_bounds__(256) void eik_fused4(const float* __restrict__ u,
                                                  const float* __restrict__ f,
                                                  float* __restrict__ un) {
    __shared__ float su[2][IN3];          // 2 x 32000 B = 64000 B

    int bx = blockIdx.x % NT;
    int by = (blockIdx.x / NT) % NT;
    int bz = blockIdx.x / (NT * NT);
    int gx0 = bx * TS - S;
    int gy0 = by * TS - S;
    int gz0 = bz * TS - S;

    // ---- stage 20^3 input tile (BIG outside domain) ----
    for (int idx = threadIdx.x; idx < IN3; idx += 256) {
        int lz  = idx / IN2;
        int rem = idx % IN2;
        int ly  = rem / IN;
        int lx  = rem % IN;
        int gx = gx0 + lx, gy = gy0 + ly, gz = gz0 + lz;
        bool inside = ((unsigned)gx < N) && ((unsigned)gy < N) && ((unsigned)gz < N);
        su[0][idx] = inside ? u[(gz * N + gy) * N + gx] : BIGV;
    }
    __syncthreads();

    // ---- 4 in-LDS Jacobi sub-steps, shrinking regions ----
    substep<18, 1>(su[0], su[1], f, gx0, gy0, gz0); __syncthreads();
    substep<16, 2>(su[1], su[0], f, gx0, gy0, gz0); __syncthreads();
    substep<14, 3>(su[0], su[1], f, gx0, gy0, gz0); __syncthreads();
    substep<12, 4>(su[1], su[0], f, gx0, gy0, gz0); __syncthreads();

    // ---- write back 12^3 output tile (local [4,16)^3, always inside) ----
    for (int idx = threadIdx.x; idx < TS * TS * TS; idx += 256) {
        int lz  = idx / (TS * TS) + S;
        int rem = idx % (TS * TS);
        int ly  = rem / TS + S;
        int lx  = rem % TS + S;
        int gx = gx0 + lx, gy = gy0 + ly, gz = gz0 + lz;
        un[(gz * N + gy) * N + gx] = su[0][(lz * IN + ly) * IN + lx];
    }
}

extern "C" void kernel_launch(void* const* d_in, const int* in_sizes, int n_in,
                              void* d_out, int out_size, void* d_ws, size_t ws_size,
                              hipStream_t stream) {
    const float* f = (const float*)d_in[0];
    float* A = (float*)d_out;   // final result lands here (72 dispatches, even)
    float* B = (float*)d_ws;

    eik_init<<<N3 / 256, 256, 0, stream>>>(A);

    const int nblk = NT * NT * NT;  // 512
    for (int d = 0; d < NDISP; ++d) {
        const float* src = (d & 1) ? B : A;
        float*       dst = (d & 1) ? A : B;
        eik_fused4<<<nblk, 256, 0, stream>>>(src, f, dst);
    }
}